// Round 1
// baseline (1721.496 us; speedup 1.0000x reference)
//
#include <hip/hip_runtime.h>
#include <math.h>

#define NT 64
#define KN 48
#define TOBS 30
#define NPRED 15
#define EMB 64
#define NODE 128
#define EDGE 256
#define ATTD 64
#define CNN 512
#define GNN 1024
#define GTT 512
#define KKA 320
#define TMAX 44

typedef _Float16 f16;
typedef f16 f16x8 __attribute__((ext_vector_type(8)));
typedef float f32x4 __attribute__((ext_vector_type(4)));

__device__ __forceinline__ float sigm(float x) {
  return 1.f / (1.f + __expf(-x));
}
__device__ __forceinline__ float tanh_f(float x) {
  float xx = fminf(fmaxf(x, -20.f), 20.f);
  float e = __expf(-2.f * xx);
  return (1.f - e) / (1.f + e);
}

// ---------------- prep: pack weights to f16, combine biases, precompute gates ----------------
__global__ __launch_bounds__(256) void prep_kernel(
    const float* __restrict__ Wih_n, const float* __restrict__ Whh_n,
    const float* __restrict__ bih_n, const float* __restrict__ bhh_n,
    const float* __restrict__ Wih_t, const float* __restrict__ Whh_t,
    const int* __restrict__ t_hist, const int* __restrict__ n_hist,
    f16* __restrict__ Wn, f16* __restrict__ Wt, float* __restrict__ bias_n,
    int* __restrict__ gt_arr, int* __restrict__ gn_arr, float* __restrict__ cn_arr)
{
  const int gid = blockIdx.x * 256 + threadIdx.x;
  const int nthr = gridDim.x * 256;
  // Wn[col][k]: col<1024 gate-cols, k<320 (0..63 = Wih_n.T row part, 64..319 = Whh_n.T)
  for (int idx = gid; idx < GNN * KKA; idx += nthr) {
    const int col = idx / KKA, k = idx - col * KKA;
    const float v = (k < EMB) ? Wih_n[col * EMB + k] : Whh_n[col * EDGE + (k - EMB)];
    Wn[idx] = (f16)v;
  }
  // Wt[col][k]: col<512, k<192
  for (int idx = gid; idx < GTT * 192; idx += nthr) {
    const int col = idx / 192, k = idx - col * 192;
    const float v = (k < EMB) ? Wih_t[col * EMB + k] : Whh_t[col * NODE + (k - EMB)];
    Wt[idx] = (f16)v;
  }
  for (int idx = gid; idx < GNN; idx += nthr) bias_n[idx] = bih_n[idx] + bhh_n[idx];

  if (blockIdx.x == 0 && threadIdx.x < TMAX) {
    const int t = threadIdx.x + 1;
    int any_t = 0, cnt = 0;
    if (t < TOBS) {
      const int thr = TOBS - t;
      for (int nn = 0; nn < NT; ++nn) any_t |= (t_hist[nn] > thr) ? 1 : 0;
      for (int m = 0; m < NT * KN; ++m) cnt += (n_hist[m] > thr) ? 1 : 0;
    } else { any_t = 1; cnt = NT * KN; }
    gt_arr[t] = any_t;
    gn_arr[t] = (any_t && cnt > 0) ? 1 : 0;
    cn_arr[t] = (float)cnt;
  }
}

// ---------------- main: one workgroup per target, full 44-step chain ----------------
__global__ __launch_bounds__(512, 2) void model_kernel(
    const float* __restrict__ img, const float* __restrict__ tabs,
    const float* __restrict__ trel, const float* __restrict__ tstep,
    const float* __restrict__ nabs_g, const float* __restrict__ nstep_g,
    const int* __restrict__ thist_g, const int* __restrict__ nhist_g,
    const float* __restrict__ W_disp, const float* __restrict__ b_disp,
    const float* __restrict__ bih_t, const float* __restrict__ bhh_t,
    const float* __restrict__ W_att_t, const float* __restrict__ b_att_t,
    const float* __restrict__ W_att_n, const float* __restrict__ b_att_n,
    const float* __restrict__ W_pred, const float* __restrict__ b_pred,
    const f16* __restrict__ Wn, const f16* __restrict__ Wt,
    const float* __restrict__ bias_n,
    const int* __restrict__ gt_arr, const int* __restrict__ gn_arr,
    const float* __restrict__ cn_arr,
    float* __restrict__ out)
{
  __shared__ f16 Ax[KN][EMB + 8];    // x part of A (k-contig, padded vs bank conflicts)
  __shared__ f16 Ah[KN][EDGE + 8];   // h part of A (current nearby hidden, f16)
  __shared__ float s_tht[NODE], s_tct[NODE];
  __shared__ float s_Ht[EDGE];
  __shared__ float s_xt[EMB];
  __shared__ float s_g[GTT];
  __shared__ float s_at[ATTD];
  __shared__ float s_sc[KN], s_w[KN];
  __shared__ float s_scal[8];        // [0..1]=cabs [2..3]=crel [4..5]=cstep [6..7]=pred_out
  __shared__ float s_pimg[2];
  __shared__ int   s_nh[KN];

  const int tid  = threadIdx.x;
  const int n    = blockIdx.x;
  const int w    = tid >> 6;
  const int lane = tid & 63;
  const int cl   = lane & 15;
  const int kq   = lane >> 4;   // 0..3
  const int koff = kq * 8;

  for (int i = tid; i < KN * EDGE; i += 512) Ah[i >> 8][i & 255] = (f16)0.f;
  for (int i = tid; i < NODE; i += 512) { s_tht[i] = 0.f; s_tct[i] = 0.f; }
  for (int i = tid; i < EDGE; i += 512) s_Ht[i] = 0.f;
  if (tid < KN) s_nh[tid] = nhist_g[n * KN + tid];
  if (tid < 8) s_scal[tid] = 0.f;
  const int thist = thist_g[n];

  // img @ W_pred part of pred_out (constant across steps) + b_pred
  if (w < 2) {
    float s = 0.f;
    for (int j = lane; j < CNN; j += 64) s += img[n * CNN + j] * W_pred[w * 896 + 128 + j];
    for (int off = 32; off; off >>= 1) s += __shfl_down(s, off);
    if (lane == 0) s_pimg[w] = s + b_pred[w];
  }

  // per-lane persistent nearby cell state + hoisted per-lane constants
  float creg[2][3][4];
  #pragma unroll
  for (int a = 0; a < 2; ++a)
    #pragma unroll
    for (int b = 0; b < 3; ++b)
      #pragma unroll
      for (int c = 0; c < 4; ++c) creg[a][b][c] = 0.f;

  float bias_q[2][4];
  const f16* bptr[2][4];
  #pragma unroll
  for (int qi = 0; qi < 2; ++qi) {
    const int q = w + qi * 8;
    #pragma unroll
    for (int g = 0; g < 4; ++g) {
      const int col = g * 256 + q * 16 + cl;
      bias_q[qi][g] = bias_n[col];
      bptr[qi][g] = Wn + (size_t)col * KKA + koff;
    }
  }
  __syncthreads();

  for (int t = 1; t <= TMAX; ++t) {
    const bool is_obs = (t < TOBS);
    const int tc = is_obs ? t : (TOBS - 1);
    const int gate_t = gt_arr[t];
    const int gate_n = gn_arr[t];
    const float currN = cn_arr[t];

    // ---- pred_out (uses previous tht/Ht), then c-state updates ----
    if (!is_obs) {
      if (w < 2) {
        float s = 0.f;
        for (int j = lane; j < NODE; j += 64) s += s_tht[j] * W_pred[w * 896 + j];
        for (int j = lane; j < EDGE; j += 64) s += s_Ht[j] * W_pred[w * 896 + 640 + j];
        for (int off = 32; off; off >>= 1) s += __shfl_down(s, off);
        if (lane == 0) s_scal[6 + w] = s + s_pimg[w];
      }
      __syncthreads();
    }
    if (tid < 2) {
      const int d = tid;
      float cabs, crel, cstepv;
      if (is_obs) {
        cabs   = tabs[(n * TOBS + tc) * 2 + d];
        crel   = trel[(n * TOBS + tc) * 2 + d];
        cstepv = tstep[(n * TOBS + tc) * 2 + d];
      } else {
        const float p = s_scal[6 + d];
        cabs   = s_scal[d] + p;
        crel   = s_scal[2 + d] + p;
        cstepv = p;
      }
      s_scal[d] = cabs; s_scal[2 + d] = crel; s_scal[4 + d] = cstepv;
      if (t >= TOBS) out[(n * NPRED + (t - TOBS)) * 2 + d] = crel;
    }

    // ---- stage nearby x = nstep @ W_disp.T + b_disp (frozen after t=30) ----
    if (t <= TOBS) {
      for (int i = tid; i < KN * EMB; i += 512) {
        const int k = i >> 6, e = i & 63;
        const float s0 = nstep_g[((n * KN + k) * TOBS + tc) * 2 + 0];
        const float s1 = nstep_g[((n * KN + k) * TOBS + tc) * 2 + 1];
        Ax[k][e] = (f16)(s0 * W_disp[e * 2] + s1 * W_disp[e * 2 + 1] + b_disp[e]);
      }
    }
    __syncthreads();

    // ---- nearby LSTM: gates[48][1024] = [Ax|Ah](48x320) @ Wn(320x1024) via MFMA ----
    if (gate_n) {
      f32x4 acc[2][3][4];
      #pragma unroll
      for (int qi = 0; qi < 2; ++qi)
        #pragma unroll
        for (int rt = 0; rt < 3; ++rt)
          #pragma unroll
          for (int g = 0; g < 4; ++g) acc[qi][rt][g] = (f32x4){0.f, 0.f, 0.f, 0.f};

      #pragma unroll
      for (int kk = 0; kk < 10; ++kk) {
        f16x8 af[3];
        #pragma unroll
        for (int rt = 0; rt < 3; ++rt) {
          const int row = rt * 16 + cl;
          const f16* ap = (kk < 2) ? &Ax[row][kk * 32 + koff]
                                   : &Ah[row][(kk - 2) * 32 + koff];
          af[rt] = *(const f16x8*)ap;
        }
        #pragma unroll
        for (int qi = 0; qi < 2; ++qi) {
          #pragma unroll
          for (int g = 0; g < 4; ++g) {
            const f16x8 bf = *(const f16x8*)(bptr[qi][g] + kk * 32);
            #pragma unroll
            for (int rt = 0; rt < 3; ++rt)
              acc[qi][rt][g] = __builtin_amdgcn_mfma_f32_16x16x32_f16(af[rt], bf, acc[qi][rt][g], 0, 0, 0);
          }
        }
      }
      __syncthreads();   // all Ah reads complete before h rewrite

      #pragma unroll
      for (int qi = 0; qi < 2; ++qi) {
        const int e = (w + qi * 8) * 16 + cl;   // hidden dim 0..255
        #pragma unroll
        for (int rt = 0; rt < 3; ++rt) {
          #pragma unroll
          for (int jj = 0; jj < 4; ++jj) {
            const int row = rt * 16 + kq * 4 + jj;
            const bool nm = is_obs ? (s_nh[row] > (TOBS - t)) : true;
            if (nm) {
              const float iv = acc[qi][rt][0][jj] + bias_q[qi][0];
              const float fv = acc[qi][rt][1][jj] + bias_q[qi][1];
              const float gv = acc[qi][rt][2][jj] + bias_q[qi][2];
              const float ov = acc[qi][rt][3][jj] + bias_q[qi][3];
              const float c2 = sigm(fv) * creg[qi][rt][jj] + sigm(iv) * tanh_f(gv);
              creg[qi][rt][jj] = c2;
              Ah[row][e] = (f16)(sigm(ov) * tanh_f(c2));
            }
          }
        }
      }
      __syncthreads();
    }

    // ---- target LSTM (1 row, fp32 accumulate, f16 weights) ----
    const bool tmask = is_obs ? (thist > (TOBS - t)) : true;
    if (gate_t && tmask) {
      if (tid < EMB)
        s_xt[tid] = s_scal[4] * W_disp[tid * 2] + s_scal[5] * W_disp[tid * 2 + 1] + b_disp[tid];
      __syncthreads();
      {
        float g = bih_t[tid] + bhh_t[tid];
        const f16x8* wp = (const f16x8*)(Wt + tid * 192);
        #pragma unroll
        for (int c8 = 0; c8 < 24; ++c8) {
          const f16x8 wv = wp[c8];
          #pragma unroll
          for (int j = 0; j < 8; ++j) {
            const int k = c8 * 8 + j;
            const float inv = (k < EMB) ? s_xt[k] : s_tht[k - EMB];
            g += (float)wv[j] * inv;
          }
        }
        s_g[tid] = g;
      }
      __syncthreads();
      if (tid < NODE) {
        const float iv = s_g[tid], fv = s_g[NODE + tid];
        const float gv = s_g[2 * NODE + tid], ov = s_g[3 * NODE + tid];
        const float c2 = sigm(fv) * s_tct[tid] + sigm(iv) * tanh_f(gv);
        s_tct[tid] = c2;
        s_tht[tid] = sigm(ov) * tanh_f(c2);
      }
      __syncthreads();
    }

    // ---- attention + Ht ----
    if (gate_n) {
      if (tid < ATTD)
        s_at[tid] = s_scal[2] * W_att_t[tid * 2] + s_scal[3] * W_att_t[tid * 2 + 1] + b_att_t[tid];
      __syncthreads();
      if (tid < KN) {
        const int k = tid;
        const float a0 = nabs_g[((n * KN + k) * TOBS + tc) * 2 + 0] - s_scal[0];
        const float a1 = nabs_g[((n * KN + k) * TOBS + tc) * 2 + 1] - s_scal[1];
        const bool nm = is_obs ? (s_nh[k] > (TOBS - t)) : true;
        float sc = 0.f;
        for (int a = 0; a < ATTD; ++a)
          sc += (a0 * W_att_n[a * 2] + a1 * W_att_n[a * 2 + 1] + b_att_n[a]) * s_at[a];
        sc *= currN * 0.125f;          // * currN / sqrt(ATT)
        s_sc[k] = nm ? sc : 0.f;       // sc * mf
        s_w[k]  = nm ? 1.f : 0.f;      // mf
      }
      __syncthreads();
      if (tid == 0) {
        float mx = s_sc[0];
        for (int k = 1; k < KN; ++k) mx = fmaxf(mx, s_sc[k]);
        float sum = 0.f;
        for (int k = 0; k < KN; ++k) {
          const float v = __expf(s_sc[k] - mx) * s_w[k];
          s_sc[k] = v; sum += v;
        }
        const float inv = 1.f / (sum + 1e-6f);
        for (int k = 0; k < KN; ++k) s_w[k] = s_sc[k] * inv;
      }
      __syncthreads();
      if (tid < EDGE) {
        float h = 0.f;
        for (int k = 0; k < KN; ++k) h += (float)Ah[k][tid] * s_w[k];
        s_Ht[tid] = h;
      }
      __syncthreads();
    }
  }
}

extern "C" void kernel_launch(void* const* d_in, const int* in_sizes, int n_in,
                              void* d_out, int out_size, void* d_ws, size_t ws_size,
                              hipStream_t stream) {
  const float* img    = (const float*)d_in[0];
  const float* tabs   = (const float*)d_in[1];
  const float* trel   = (const float*)d_in[2];
  const float* tstep  = (const float*)d_in[3];
  const float* nabs   = (const float*)d_in[4];
  const float* nstep  = (const float*)d_in[6];
  const int*   thist  = (const int*)d_in[7];
  const int*   nhist  = (const int*)d_in[8];
  const float* W_disp = (const float*)d_in[9];
  const float* b_disp = (const float*)d_in[10];
  const float* Wih_t  = (const float*)d_in[11];
  const float* Whh_t  = (const float*)d_in[12];
  const float* bih_t  = (const float*)d_in[13];
  const float* bhh_t  = (const float*)d_in[14];
  const float* Wih_n  = (const float*)d_in[15];
  const float* Whh_n  = (const float*)d_in[16];
  const float* bih_n  = (const float*)d_in[17];
  const float* bhh_n  = (const float*)d_in[18];
  const float* W_att_t = (const float*)d_in[19];
  const float* b_att_t = (const float*)d_in[20];
  const float* W_att_n = (const float*)d_in[21];
  const float* b_att_n = (const float*)d_in[22];
  const float* W_pred  = (const float*)d_in[23];
  const float* b_pred  = (const float*)d_in[24];

  char* ws = (char*)d_ws;
  f16*   Wn     = (f16*)(ws);             // 1024*320*2 = 655360
  f16*   Wt     = (f16*)(ws + 655360);    // 512*192*2  = 196608
  float* bias_n = (float*)(ws + 851968);  // 4096
  int*   gt_arr = (int*)(ws + 856064);    // 192
  int*   gn_arr = (int*)(ws + 856256);    // 192
  float* cn_arr = (float*)(ws + 856448);  // 192

  prep_kernel<<<64, 256, 0, stream>>>(Wih_n, Whh_n, bih_n, bhh_n, Wih_t, Whh_t,
                                      thist, nhist, Wn, Wt, bias_n,
                                      gt_arr, gn_arr, cn_arr);
  model_kernel<<<NT, 512, 0, stream>>>(img, tabs, trel, tstep, nabs, nstep,
                                       thist, nhist, W_disp, b_disp,
                                       bih_t, bhh_t, W_att_t, b_att_t,
                                       W_att_n, b_att_n, W_pred, b_pred,
                                       Wn, Wt, bias_n, gt_arr, gn_arr, cn_arr,
                                       (float*)d_out);
}